// Round 2
// baseline (106.294 us; speedup 1.0000x reference)
//
#include <hip/hip_runtime.h>

namespace {

constexpr int IMGW = 512;
constexpr int NIMG = 16;
constexpr int C1N  = 16;
constexpr int C2N  = 32;
constexpr int NBLK = 512;         // 16 images * 32 blocks; each block = 2 patch-rows
constexpr int PART = C1N * 9;     // 144 partial scalars per block

// Orthonormal 8-pt DCT-II constants
__device__ __forceinline__ void dct8(const float x[8], float o[8]) {
  const float c1 = 0.49039264020161522f;
  const float c2 = 0.46193976625564337f;
  const float c3 = 0.41573480615127262f;
  const float c4 = 0.35355339059327373f;
  const float c5 = 0.27778511650980111f;
  const float c6 = 0.19134171618254492f;
  const float c7 = 0.09754516100806413f;
  const float s0 = x[0] + x[7], s1 = x[1] + x[6], s2 = x[2] + x[5], s3 = x[3] + x[4];
  const float d0 = x[0] - x[7], d1 = x[1] - x[6], d2 = x[2] - x[5], d3 = x[3] - x[4];
  const float e0 = s0 + s3, e1 = s1 + s2, e2 = s0 - s3, e3 = s1 - s2;
  o[0] = c4 * (e0 + e1);
  o[4] = c4 * (e0 - e1);
  o[2] = fmaf(c2, e2,  c6 * e3);
  o[6] = fmaf(c6, e2, -(c2 * e3));
  o[1] = fmaf(c1, d0, fmaf( c3, d1, fmaf( c5, d2,  c7 * d3)));
  o[3] = fmaf(c3, d0, fmaf(-c7, d1, fmaf(-c1, d2, -(c5 * d3))));
  o[5] = fmaf(c5, d0, fmaf(-c1, d1, fmaf( c7, d2,  c3 * d3)));
  o[7] = fmaf(c7, d0, fmaf(-c5, d1, fmaf( c3, d2, -(c1 * d3))));
}

// DCT(2D) + conv1(4 channels) + ReLU + border-class accumulation for one
// 8x8 patch held in registers. Everything statically indexed (full unroll).
__device__ __forceinline__ void process_patch(
    const float p[8][8], const float w[4][9], const float bb[4], float acc[36])
{
  // pass 1: t = D * p  (contract over row index), column-wise
  float t[8][8];
  #pragma unroll
  for (int j = 0; j < 8; ++j) {
    float xin[8], xo[8];
    #pragma unroll
    for (int k = 0; k < 8; ++k) xin[k] = p[k][j];
    dct8(xin, xo);
    #pragma unroll
    for (int k = 0; k < 8; ++k) t[k][j] = xo[k];
  }
  // pass 2: cf = t * D^T, row-wise
  float cf[8][8];
  #pragma unroll
  for (int i = 0; i < 8; ++i) {
    float xo[8];
    dct8(t[i], xo);
    #pragma unroll
    for (int k = 0; k < 8; ++k) cf[i][k] = xo[k];
  }

  // conv1 3x3 SAME + ReLU; accumulate 9 border-class sums per channel.
  #pragma unroll
  for (int cc = 0; cc < 4; ++cc) {
    #pragma unroll
    for (int i = 0; i < 8; ++i) {
      #pragma unroll
      for (int j = 0; j < 8; ++j) {
        float a = bb[cc];
        #pragma unroll
        for (int di = 0; di < 3; ++di) {
          const int ii = i + di - 1;
          if (ii >= 0 && ii < 8) {
            #pragma unroll
            for (int dj = 0; dj < 3; ++dj) {
              const int jj = j + dj - 1;
              if (jj >= 0 && jj < 8) a = fmaf(w[cc][di * 3 + dj], cf[ii][jj], a);
            }
          }
        }
        a = fmaxf(a, 0.f);
        acc[cc * 9 + 0] += a;                       // T
        if (i == 0) acc[cc * 9 + 1] += a;           // R0
        if (i == 7) acc[cc * 9 + 2] += a;           // R7
        if (j == 0) acc[cc * 9 + 3] += a;           // C0
        if (j == 7) acc[cc * 9 + 4] += a;           // C7
        if (i == 0 && j == 0) acc[cc * 9 + 5] += a; // K00
        if (i == 0 && j == 7) acc[cc * 9 + 6] += a; // K07
        if (i == 7 && j == 0) acc[cc * 9 + 7] += a; // K70
        if (i == 7 && j == 7) acc[cc * 9 + 8] += a; // K77
      }
    }
  }
}

// One block = 2 patch-rows (128 patches) of one image; 4 waves.
// lane = patch column; wave = channel quartet. Both patches' loads issue
// up front; compiler overlaps patch-1 latency under patch-0 compute.
__global__ __launch_bounds__(256, 2) void dct_conv_kernel(
    const float* __restrict__ x, const float* __restrict__ w1,
    const float* __restrict__ b1, float* __restrict__ partials)
{
  const int blk  = blockIdx.x;
  const int img  = blk >> 5;
  const int pr2  = (blk & 31) * 2;     // first of two patch-rows
  const int lane = threadIdx.x & 63;
  const int wave = threadIdx.x >> 6;

  const float* base0 = x + ((size_t)img * IMGW + (size_t)pr2 * 8) * IMGW + (size_t)lane * 8;
  const float* base1 = base0 + (size_t)8 * IMGW;

  float p0[8][8], p1[8][8];
  #pragma unroll
  for (int r = 0; r < 8; ++r) {
    const float4 a = *reinterpret_cast<const float4*>(base0 + (size_t)r * IMGW);
    const float4 b = *reinterpret_cast<const float4*>(base0 + (size_t)r * IMGW + 4);
    p0[r][0] = a.x; p0[r][1] = a.y; p0[r][2] = a.z; p0[r][3] = a.w;
    p0[r][4] = b.x; p0[r][5] = b.y; p0[r][6] = b.z; p0[r][7] = b.w;
  }
  #pragma unroll
  for (int r = 0; r < 8; ++r) {
    const float4 a = *reinterpret_cast<const float4*>(base1 + (size_t)r * IMGW);
    const float4 b = *reinterpret_cast<const float4*>(base1 + (size_t)r * IMGW + 4);
    p1[r][0] = a.x; p1[r][1] = a.y; p1[r][2] = a.z; p1[r][3] = a.w;
    p1[r][4] = b.x; p1[r][5] = b.y; p1[r][6] = b.z; p1[r][7] = b.w;
  }

  float w[4][9], bb[4];
  #pragma unroll
  for (int cc = 0; cc < 4; ++cc) {
    const int ch = wave * 4 + cc;
    #pragma unroll
    for (int q = 0; q < 9; ++q) w[cc][q] = w1[ch * 9 + q];
    bb[cc] = b1[ch];
  }

  float acc[36];
  #pragma unroll
  for (int q = 0; q < 36; ++q) acc[q] = 0.f;

  process_patch(p0, w, bb, acc);
  process_patch(p1, w, bb, acc);

  // one wave-reduction per 2 patches
  #pragma unroll
  for (int q = 0; q < 36; ++q) {
    float s = acc[q];
    #pragma unroll
    for (int m = 32; m >= 1; m >>= 1) s += __shfl_xor(s, m, 64);
    acc[q] = s;
  }
  if (lane == 0) {
    #pragma unroll
    for (int cc = 0; cc < 4; ++cc)
      #pragma unroll
      for (int q = 0; q < 9; ++q)
        partials[(size_t)blk * PART + (wave * 4 + cc) * 9 + q] = acc[cc * 9 + q];
  }
}

// Per image: sum the 32 block-partials (fixed order, deterministic), then
// contract with w2 via inclusion-exclusion border sums.
__global__ __launch_bounds__(192) void finish_kernel(
    const float* __restrict__ w2, const float* __restrict__ b2,
    const float* __restrict__ partials, float* __restrict__ out)
{
  const int img = blockIdx.x;
  const int tid = threadIdx.x;
  __shared__ float acc[C1N][9];
  if (tid < PART) {
    float s = 0.f;
    for (int k = 0; k < 32; ++k) s += partials[(size_t)(img * 32 + k) * PART + tid];
    acc[tid / 9][tid % 9] = s;
  }
  __syncthreads();
  if (tid < C2N) {
    float r = 0.f;
    for (int c1 = 0; c1 < C1N; ++c1) {
      const float T  = acc[c1][0], R0 = acc[c1][1], R7 = acc[c1][2];
      const float Q0 = acc[c1][3], Q7 = acc[c1][4];
      const float K00 = acc[c1][5], K07 = acc[c1][6], K70 = acc[c1][7], K77 = acc[c1][8];
      const float* wp = w2 + (size_t)(tid * C1N + c1) * 9;
      #pragma unroll
      for (int di = 0; di < 3; ++di) {
        #pragma unroll
        for (int dj = 0; dj < 3; ++dj) {
          float S = T;
          if (di == 0) S -= R7;
          if (di == 2) S -= R0;
          if (dj == 0) S -= Q7;
          if (dj == 2) S -= Q0;
          if (di == 0 && dj == 0) S += K77;
          if (di == 0 && dj == 2) S += K70;
          if (di == 2 && dj == 0) S += K07;
          if (di == 2 && dj == 2) S += K00;
          r = fmaf(wp[di * 3 + dj], S, r);
        }
      }
    }
    out[img * C2N + tid] = b2[tid] + r * (1.0f / 262144.0f);
  }
}

} // namespace

extern "C" void kernel_launch(void* const* d_in, const int* in_sizes, int n_in,
                              void* d_out, int out_size, void* d_ws, size_t ws_size,
                              hipStream_t stream) {
  const float* x  = (const float*)d_in[0];
  const float* w1 = (const float*)d_in[1];
  const float* b1 = (const float*)d_in[2];
  const float* w2 = (const float*)d_in[3];
  const float* b2 = (const float*)d_in[4];
  float* out      = (float*)d_out;
  float* partials = (float*)d_ws;   // NBLK * PART floats = 288 KB

  dct_conv_kernel<<<NBLK, 256, 0, stream>>>(x, w1, b1, partials);
  finish_kernel<<<NIMG, 192, 0, stream>>>(w2, b2, partials, out);
}

// Round 3
// 40.652 us; speedup vs baseline: 2.6147x; 2.6147x over previous
//
#include <hip/hip_runtime.h>

namespace {

constexpr int IMGW = 512;
constexpr int NIMG = 16;
constexpr int C1N  = 16;
constexpr int C2N  = 32;
constexpr int NBLK = 2048;        // 1024 patch-rows x 2 channel-octets
constexpr int PART = C1N * 9;     // 144 partial scalars per patch-row

// Fast orthonormal 8-pt DCT-II (even/odd butterfly, ~34 ops vs 128).
__device__ __forceinline__ void dct8(const float x[8], float o[8]) {
  const float c1 = 0.49039264020161522f;
  const float c2 = 0.46193976625564337f;
  const float c3 = 0.41573480615127262f;
  const float c4 = 0.35355339059327373f;
  const float c5 = 0.27778511650980111f;
  const float c6 = 0.19134171618254492f;
  const float c7 = 0.09754516100806413f;
  const float s0 = x[0] + x[7], s1 = x[1] + x[6], s2 = x[2] + x[5], s3 = x[3] + x[4];
  const float d0 = x[0] - x[7], d1 = x[1] - x[6], d2 = x[2] - x[5], d3 = x[3] - x[4];
  const float e0 = s0 + s3, e1 = s1 + s2, e2 = s0 - s3, e3 = s1 - s2;
  o[0] = c4 * (e0 + e1);
  o[4] = c4 * (e0 - e1);
  o[2] = fmaf(c2, e2,  c6 * e3);
  o[6] = fmaf(c6, e2, -(c2 * e3));
  o[1] = fmaf(c1, d0, fmaf( c3, d1, fmaf( c5, d2,  c7 * d3)));
  o[3] = fmaf(c3, d0, fmaf(-c7, d1, fmaf(-c1, d2, -(c5 * d3))));
  o[5] = fmaf(c5, d0, fmaf(-c1, d1, fmaf( c7, d2,  c3 * d3)));
  o[7] = fmaf(c7, d0, fmaf(-c5, d1, fmaf( c3, d2, -(c1 * d3))));
}

// One block = one patch-row (64 patches) x 8 channels; 4 waves.
// lane = patch column; wave = channel PAIR within this block's octet.
// 8192 waves total -> ~2x resident waves vs quartet split, for latency hiding.
// Per-channel we only need 9 scalars (T, R0, R7, C0, C7, 4 corners);
// conv2 + both means are linear and fold into the finish kernel.
__global__ __launch_bounds__(256) void dct_conv_kernel(
    const float* __restrict__ x, const float* __restrict__ w1,
    const float* __restrict__ b1, float* __restrict__ partials)
{
  const int blk   = blockIdx.x;
  const int prow  = blk >> 1;          // 0..1023 (img*64 + row)
  const int img   = prow >> 6;
  const int row   = prow & 63;
  const int octet = blk & 1;           // channels 8*octet .. 8*octet+7
  const int lane  = threadIdx.x & 63;  // patch column
  const int wave  = threadIdx.x >> 6;  // 0..3 -> channel pair

  const int ch0 = octet * 8 + wave * 2;

  // weights first (scalar loads, SGPR-cached per wave)
  float w[2][9], bb[2];
  #pragma unroll
  for (int cc = 0; cc < 2; ++cc) {
    #pragma unroll
    for (int q = 0; q < 9; ++q) w[cc][q] = w1[(ch0 + cc) * 9 + q];
    bb[cc] = b1[ch0 + cc];
  }

  const float* base = x + ((size_t)img * IMGW + (size_t)row * 8) * IMGW + (size_t)lane * 8;

  float p[8][8];
  #pragma unroll
  for (int r = 0; r < 8; ++r) {
    const float4 a = *reinterpret_cast<const float4*>(base + (size_t)r * IMGW);
    const float4 b = *reinterpret_cast<const float4*>(base + (size_t)r * IMGW + 4);
    p[r][0] = a.x; p[r][1] = a.y; p[r][2] = a.z; p[r][3] = a.w;
    p[r][4] = b.x; p[r][5] = b.y; p[r][6] = b.z; p[r][7] = b.w;
  }

  // 2D DCT: t = D*p (column-wise), cf = t*D^T (row-wise)
  float t[8][8];
  #pragma unroll
  for (int j = 0; j < 8; ++j) {
    float xin[8], xo[8];
    #pragma unroll
    for (int k = 0; k < 8; ++k) xin[k] = p[k][j];
    dct8(xin, xo);
    #pragma unroll
    for (int k = 0; k < 8; ++k) t[k][j] = xo[k];
  }
  float cf[8][8];
  #pragma unroll
  for (int i = 0; i < 8; ++i) {
    float xo[8];
    dct8(t[i], xo);
    #pragma unroll
    for (int k = 0; k < 8; ++k) cf[i][k] = xo[k];
  }

  // conv1 3x3 SAME + ReLU for 2 channels; 9 border-class accumulators each.
  float acc[18];
  #pragma unroll
  for (int q = 0; q < 18; ++q) acc[q] = 0.f;

  #pragma unroll
  for (int cc = 0; cc < 2; ++cc) {
    #pragma unroll
    for (int i = 0; i < 8; ++i) {
      #pragma unroll
      for (int j = 0; j < 8; ++j) {
        float a = bb[cc];
        #pragma unroll
        for (int di = 0; di < 3; ++di) {
          const int ii = i + di - 1;
          if (ii >= 0 && ii < 8) {
            #pragma unroll
            for (int dj = 0; dj < 3; ++dj) {
              const int jj = j + dj - 1;
              if (jj >= 0 && jj < 8) a = fmaf(w[cc][di * 3 + dj], cf[ii][jj], a);
            }
          }
        }
        a = fmaxf(a, 0.f);
        acc[cc * 9 + 0] += a;                       // T
        if (i == 0) acc[cc * 9 + 1] += a;           // R0
        if (i == 7) acc[cc * 9 + 2] += a;           // R7
        if (j == 0) acc[cc * 9 + 3] += a;           // C0
        if (j == 7) acc[cc * 9 + 4] += a;           // C7
        if (i == 0 && j == 0) acc[cc * 9 + 5] = a;  // K00 (single pixel)
        if (i == 0 && j == 7) acc[cc * 9 + 6] = a;  // K07
        if (i == 7 && j == 0) acc[cc * 9 + 7] = a;  // K70
        if (i == 7 && j == 7) acc[cc * 9 + 8] = a;  // K77
      }
    }
  }

  // reduce across 64 lanes (64 patches)
  #pragma unroll
  for (int q = 0; q < 18; ++q) {
    float s = acc[q];
    #pragma unroll
    for (int m = 32; m >= 1; m >>= 1) s += __shfl_xor(s, m, 64);
    acc[q] = s;
  }
  if (lane == 0) {
    #pragma unroll
    for (int cc = 0; cc < 2; ++cc)
      #pragma unroll
      for (int q = 0; q < 9; ++q)
        partials[(size_t)prow * PART + (ch0 + cc) * 9 + q] = acc[cc * 9 + q];
  }
}

// Per image: sum the 64 patch-row partials (fixed order, deterministic), then
// contract with w2 via inclusion-exclusion border sums.
__global__ __launch_bounds__(192) void finish_kernel(
    const float* __restrict__ w2, const float* __restrict__ b2,
    const float* __restrict__ partials, float* __restrict__ out)
{
  const int img = blockIdx.x;
  const int tid = threadIdx.x;
  __shared__ float acc[C1N][9];
  if (tid < PART) {
    float s = 0.f;
    for (int k = 0; k < 64; ++k) s += partials[(size_t)(img * 64 + k) * PART + tid];
    acc[tid / 9][tid % 9] = s;
  }
  __syncthreads();
  if (tid < C2N) {
    float r = 0.f;
    for (int c1 = 0; c1 < C1N; ++c1) {
      const float T  = acc[c1][0], R0 = acc[c1][1], R7 = acc[c1][2];
      const float Q0 = acc[c1][3], Q7 = acc[c1][4];
      const float K00 = acc[c1][5], K07 = acc[c1][6], K70 = acc[c1][7], K77 = acc[c1][8];
      const float* wp = w2 + (size_t)(tid * C1N + c1) * 9;
      #pragma unroll
      for (int di = 0; di < 3; ++di) {
        #pragma unroll
        for (int dj = 0; dj < 3; ++dj) {
          float S = T;
          if (di == 0) S -= R7;
          if (di == 2) S -= R0;
          if (dj == 0) S -= Q7;
          if (dj == 2) S -= Q0;
          if (di == 0 && dj == 0) S += K77;
          if (di == 0 && dj == 2) S += K70;
          if (di == 2 && dj == 0) S += K07;
          if (di == 2 && dj == 2) S += K00;
          r = fmaf(wp[di * 3 + dj], S, r);
        }
      }
    }
    out[img * C2N + tid] = b2[tid] + r * (1.0f / 262144.0f);
  }
}

} // namespace

extern "C" void kernel_launch(void* const* d_in, const int* in_sizes, int n_in,
                              void* d_out, int out_size, void* d_ws, size_t ws_size,
                              hipStream_t stream) {
  const float* x  = (const float*)d_in[0];
  const float* w1 = (const float*)d_in[1];
  const float* b1 = (const float*)d_in[2];
  const float* w2 = (const float*)d_in[3];
  const float* b2 = (const float*)d_in[4];
  float* out      = (float*)d_out;
  float* partials = (float*)d_ws;   // 1024 * PART floats = 576 KB

  dct_conv_kernel<<<NBLK, 256, 0, stream>>>(x, w1, b1, partials);
  finish_kernel<<<NIMG, 192, 0, stream>>>(w2, b2, partials, out);
}